// Round 7
// baseline (86.440 us; speedup 1.0000x reference)
//
#include <hip/hip_runtime.h>

// L2-distance causal attention with zero-KV sink.
// B=2, H=16, N=2048, D=64. fp32 in/out, bf16 MFMA internally.
//
// Round 6: NO-LDS, NO-BARRIER attend.
//   build_ws: phase 1 builds the old per-64-key-tile images in LDS
//     (slot-permuted K, transposed V^T, per-key bias); phase 2 re-linearizes
//     them FRAGMENT-MAJOR: ws[tile][frag f][lane] = the exact 16B that wave
//     lane `lane` needs for MFMA fragment f. Attend then does perfectly
//     coalesced global_load_dwordx4 straight into VGPRs.
//   attend: 2048 independent single-wave blocks (64 thr), 32 queries/wave
//     (two 16-query fragments with separate m/l/oacc). Zero __syncthreads,
//     zero LDS: waves never couple; TLP hides L2 latency. V-fragment loads
//     issued before softmax so they complete under exp2 work. Heavy waves
//     dispatch first; head index in low 5 bits pins each head's ws slice to
//     one XCD's L2 (~2.1 MB/XCD).

#define NQ 2048
#define DH 64
#define NT 32   // 64-key tiles per sequence

typedef float f32x4 __attribute__((ext_vector_type(4)));
typedef __bf16 bf16x8 __attribute__((ext_vector_type(8)));
typedef unsigned short u16x8 __attribute__((ext_vector_type(8)));

union B8 { u16x8 u; bf16x8 b; };

__device__ __forceinline__ unsigned short f2b(float f) {
  unsigned int x = __builtin_bit_cast(unsigned int, f);
  unsigned int r = x + 0x7fffu + ((x >> 16) & 1u);   // RNE to bf16
  return (unsigned short)(r >> 16);
}
__device__ __forceinline__ float b2f(unsigned short u) {
  unsigned int t = ((unsigned int)u) << 16;
  return __builtin_bit_cast(float, t);
}
__device__ __forceinline__ f32x4 vmax4(f32x4 a, f32x4 b) {
  f32x4 r;
  r[0] = fmaxf(a[0], b[0]); r[1] = fmaxf(a[1], b[1]);
  r[2] = fmaxf(a[2], b[2]); r[3] = fmaxf(a[3], b[3]);
  return r;
}

// K-slot permutation: slot s (bits c1 c0 g1 g0 r1 r0) holds key (c1 g1 g0 c0 r1 r0).
// Makes QK^T's C-layout scores be exactly the PV B-fragment values (no exchange).
__device__ __forceinline__ int kslot(int a) {
  return (a & 0x23) | ((a & 0x04) << 2) | ((a & 0x18) >> 1);
}

constexpr float QS = 0.3551784733906239f;   // 2*log2(e)/sqrt(66)
constexpr float BS = 0.17758923669531197f;  // log2(e)/sqrt(66)

// ---------------- kernel 1: build fragment-major per-tile images ----------------
__global__ __launch_bounds__(256) void build_ws(
    const float* __restrict__ k, const float* __restrict__ v,
    unsigned short* __restrict__ wsK, unsigned short* __restrict__ wsV,
    float* __restrict__ wsB)
{
  const int bh = blockIdx.x;          // 0..31
  const int t  = blockIdx.y;          // 0..31
  const int tid  = threadIdx.x;
  const int wid  = tid >> 6;
  const int lane = tid & 63;
  const int g    = lane >> 4;
  const int qi   = lane & 15;
  const size_t bhN = (size_t)bh * NQ;
  const int tile64 = t * 64;
  const size_t tileId = (size_t)bh * NT + t;
  unsigned short* KtF = wsK + tileId * 4096;
  unsigned short* VtF = wsV + tileId * 4096;
  float*          Bt  = wsB + tileId * 64;

  __shared__ __align__(16) unsigned short sK[4096];
  __shared__ __align__(16) unsigned short sV[4096];

  // ---- phase 1: old-style images into LDS (verified layout) ----
  // K image (+ bias), slot-permuted, XOR-swizzled.
#pragma unroll
  for (int i = 0; i < 4; i++) {
    int f  = i * 256 + tid;
    int kg = f >> 4, d4 = f & 15;
    int slot = kslot(kg);
    const float4* kp = (const float4*)(k + (bhN + tile64 + kg) * DH);
    float4 kk = kp[d4];
    unsigned short h0 = f2b(kk.x), h1 = f2b(kk.y), h2 = f2b(kk.z), h3 = f2b(kk.w);
    float a0 = b2f(h0), a1 = b2f(h1), a2 = b2f(h2), a3 = b2f(h3);
    float ss = a0*a0 + a1*a1 + a2*a2 + a3*a3;     // |k_bf|^2 partial
    ss += __shfl_xor(ss, 1, 64);
    ss += __shfl_xor(ss, 2, 64);
    ss += __shfl_xor(ss, 4, 64);
    ss += __shfl_xor(ss, 8, 64);
    if (d4 == 0) Bt[slot] = -BS * ss;
    unsigned int w0 = (unsigned int)h0 | ((unsigned int)h1 << 16);
    unsigned int w1 = (unsigned int)h2 | ((unsigned int)h3 << 16);
    int idx = slot * 64 + ((d4 * 4) ^ ((slot & 7) << 3));
    uint2 wv; wv.x = w0; wv.y = w1;
    *(uint2*)&sK[idx] = wv;
  }

  // V^T image (identity slot order), XOR-swizzled.
#pragma unroll
  for (int jj = 0; jj < 4; jj++) {
    int kgb = jj * 16 + wid * 4;
    const float* vp = v + (bhN + tile64 + kgb) * DH + lane;
    float x0 = vp[0], x1 = vp[DH], x2 = vp[2 * DH], x3 = vp[3 * DH];
    unsigned int w0 = (unsigned int)f2b(x0) | ((unsigned int)f2b(x1) << 16);
    unsigned int w1 = (unsigned int)f2b(x2) | ((unsigned int)f2b(x3) << 16);
    int idx = lane * 64 + (kgb ^ ((lane & 7) << 3));
    uint2 wv; wv.x = w0; wv.y = w1;
    *(uint2*)&sV[idx] = wv;
  }
  __syncthreads();

  // ---- phase 2: linearize fragment-major (exact wave read order) ----
  // K frag f=(c*2+ks): lane needs sK[(16c+qi)*64 + ((ks*32+g*8)^((qi&7)<<3))]
  // V frag f=(db*2+ks): lane needs sV[(db*16+qi)*64 + ((ks*32+g*8)^((qi&7)<<3))]
#pragma unroll
  for (int f4 = 0; f4 < 2; f4++) {
    int f  = wid * 2 + f4;           // 0..7
    int cc = f >> 1, ks = f & 1;
    int sw = ((ks * 32 + g * 8) ^ ((qi & 7) << 3));
    bf16x8 kv = *(const bf16x8*)&sK[(16 * cc + qi) * 64 + sw];
    *(bf16x8*)&KtF[(f * 64 + lane) * 8] = kv;
    bf16x8 vv = *(const bf16x8*)&sV[(cc * 16 + qi) * 64 + sw];
    *(bf16x8*)&VtF[(f * 64 + lane) * 8] = vv;
  }
}

// ---------------- kernel 2: no-LDS flash attention ----------------
__global__ __launch_bounds__(64) void attend_l2_flash(
    const float* __restrict__ q,
    const unsigned short* __restrict__ wsK,
    const unsigned short* __restrict__ wsV,
    const float* __restrict__ wsB,
    float* __restrict__ out)
{
  const int b    = blockIdx.x;        // 2048 single-wave blocks
  const int bh   = b & 31;            // b%8 == bh%8 => head pinned to one XCD
  const int w    = 63 - (b >> 5);     // 32-query slot; heavy waves first
  const int lane = threadIdx.x;
  const int g    = lane >> 4;
  const int qi   = lane & 15;
  const int qg0  = w * 32 + qi;       // fragment qf=0 query row
  const int qg1  = qg0 + 16;          // fragment qf=1 query row
  const size_t bhN = (size_t)bh * NQ;
  const int ntiles = (w >> 1) + 1;
  const size_t tbase = (size_t)bh * NT;

  // ---- Q fragments (hi/lo split), both qf, hoisted ----
  bf16x8 qhi[2][2], qlo[2][2];   // [qf][ks]
#pragma unroll
  for (int qf = 0; qf < 2; qf++) {
    const float* qrow = q + (bhN + (qf ? qg1 : qg0)) * DH;
#pragma unroll
    for (int ks = 0; ks < 2; ks++) {
      B8 th, tl;
#pragma unroll
      for (int j = 0; j < 8; j++) {
        float x = qrow[ks * 32 + g * 8 + j] * QS;
        unsigned short h = f2b(x);
        th.u[j] = h;
        tl.u[j] = f2b(x - b2f(h));
      }
      qhi[qf][ks] = th.b; qlo[qf][ks] = tl.b;
    }
  }

  f32x4 oacc[2][4] = {};          // [qf][db], O^T accumulators
  float m[2] = {0.0f, 0.0f};      // running max per fragment (sink pins >= 0)
  f32x4 l4[2] = {{0,0,0,0},{0,0,0,0}};

  const char*  Kp = (const char*)(wsK + tbase * 4096);
  const char*  Vp = (const char*)(wsV + tbase * 4096);
  const float* Bp = wsB + tbase * 64;
  const int lo16 = lane * 16;

  for (int t = 0; t < ntiles; t++) {
    // ---- K fragments + bias: coalesced L2-hot register loads ----
    bf16x8 kf[8];
#pragma unroll
    for (int f = 0; f < 8; f++)
      kf[f] = *(const bf16x8*)(Kp + f * 1024 + lo16);
    f32x4 bb[4];
#pragma unroll
    for (int c = 0; c < 4; c++)
      bb[c] = *(const f32x4*)(Bp + 16 * c + 4 * g);

    // ---- QK^T, swapped: S^T = K . Q^T ----
    f32x4 sc[2][4] = {};
#pragma unroll
    for (int c = 0; c < 4; c++) {
#pragma unroll
      for (int ks = 0; ks < 2; ks++) {
        bf16x8 ak = kf[c * 2 + ks];
        sc[0][c] = __builtin_amdgcn_mfma_f32_16x16x32_bf16(ak, qhi[0][ks], sc[0][c], 0, 0, 0);
        sc[0][c] = __builtin_amdgcn_mfma_f32_16x16x32_bf16(ak, qlo[0][ks], sc[0][c], 0, 0, 0);
        sc[1][c] = __builtin_amdgcn_mfma_f32_16x16x32_bf16(ak, qhi[1][ks], sc[1][c], 0, 0, 0);
        sc[1][c] = __builtin_amdgcn_mfma_f32_16x16x32_bf16(ak, qlo[1][ks], sc[1][c], 0, 0, 0);
      }
    }

    // ---- V fragments issued now; latency hides under softmax ----
    bf16x8 vf[8];
#pragma unroll
    for (int f = 0; f < 8; f++)
      vf[f] = *(const bf16x8*)(Vp + f * 1024 + lo16);

    // ---- softmax: s = sc + bias, causal mask on diag tile ----
    const bool diag = (t == ntiles - 1);
    const int tile64 = t * 64;
#pragma unroll
    for (int c = 0; c < 4; c++) {
      sc[0][c] += bb[c];                        // v_pk_add_f32
      sc[1][c] += bb[c];
      if (diag) {
#pragma unroll
        for (int r = 0; r < 4; r++) {
          int key = tile64 + 32 * (c >> 1) + 8 * g + 4 * (c & 1) + r; // pi(slot)
          if (key > qg0) sc[0][c][r] = -1e30f;
          if (key > qg1) sc[1][c][r] = -1e30f;
        }
      }
    }

    // ---- exact defer-max (both fragments; ~never fires, sink pins m=0) ----
    f32x4 mv0 = vmax4(vmax4(sc[0][0], sc[0][1]), vmax4(sc[0][2], sc[0][3]));
    f32x4 mv1 = vmax4(vmax4(sc[1][0], sc[1][1]), vmax4(sc[1][2], sc[1][3]));
    float ml0 = fmaxf(fmaxf(fmaxf(mv0[0], mv0[1]), mv0[2]), mv0[3]);
    float ml1 = fmaxf(fmaxf(fmaxf(mv1[0], mv1[1]), mv1[2]), mv1[3]);
    if (!__all((ml0 <= m[0]) && (ml1 <= m[1]))) {
      float mt0 = fmaxf(ml0, __shfl_xor(ml0, 16, 64));
      mt0 = fmaxf(mt0, __shfl_xor(mt0, 32, 64));
      float dm0 = fmaxf(mt0 - m[0], 0.0f);
      m[0] += dm0;
      float a0 = exp2f(-dm0);
      l4[0] *= a0;
#pragma unroll
      for (int db = 0; db < 4; db++) oacc[0][db] *= a0;
      float mt1 = fmaxf(ml1, __shfl_xor(ml1, 16, 64));
      mt1 = fmaxf(mt1, __shfl_xor(mt1, 32, 64));
      float dm1 = fmaxf(mt1 - m[1], 0.0f);
      m[1] += dm1;
      float a1 = exp2f(-dm1);
      l4[1] *= a1;
#pragma unroll
      for (int db = 0; db < 4; db++) oacc[1][db] *= a1;
    }

    // ---- weights: e = exp2(s - m); m==0 fast path skips the subtract ----
    if (__all((m[0] == 0.0f) && (m[1] == 0.0f))) {
#pragma unroll
      for (int c = 0; c < 4; c++) {
#pragma unroll
        for (int r = 0; r < 4; r++) {
          sc[0][c][r] = exp2f(sc[0][c][r]);
          sc[1][c][r] = exp2f(sc[1][c][r]);
        }
        l4[0] += sc[0][c];
        l4[1] += sc[1][c];
      }
    } else {
#pragma unroll
      for (int c = 0; c < 4; c++) {
#pragma unroll
        for (int r = 0; r < 4; r++) {
          sc[0][c][r] = exp2f(sc[0][c][r] - m[0]);
          sc[1][c][r] = exp2f(sc[1][c][r] - m[1]);
        }
        l4[0] += sc[0][c];
        l4[1] += sc[1][c];
      }
    }

    // ---- P repack (local by slot-permutation construction) ----
    B8 pr[2][2];
#pragma unroll
    for (int qf = 0; qf < 2; qf++)
#pragma unroll
      for (int j = 0; j < 8; j++) {
        pr[qf][0].b[j] = (__bf16)sc[qf][(j >> 2)][j & 3];
        pr[qf][1].b[j] = (__bf16)sc[qf][2 + (j >> 2)][j & 3];
      }

    // ---- PV: O^T += V^T . P^T ----
#pragma unroll
    for (int db = 0; db < 4; db++) {
#pragma unroll
      for (int ks = 0; ks < 2; ks++) {
        bf16x8 av = vf[db * 2 + ks];
        oacc[0][db] = __builtin_amdgcn_mfma_f32_16x16x32_bf16(av, pr[0][ks].b, oacc[0][db], 0, 0, 0);
        oacc[1][db] = __builtin_amdgcn_mfma_f32_16x16x32_bf16(av, pr[1][ks].b, oacc[1][db], 0, 0, 0);
      }
    }

    Kp += 8192; Vp += 8192; Bp += 64;
  }

  // ---- epilogue (both fragments) ----
#pragma unroll
  for (int qf = 0; qf < 2; qf++) {
    float lt = (l4[qf][0] + l4[qf][1]) + (l4[qf][2] + l4[qf][3]);
    lt += __shfl_xor(lt, 16, 64);
    lt += __shfl_xor(lt, 32, 64);
    float denom = lt + exp2f(-m[qf]);   // + sink weight
    float inv = 1.0f / denom;
    float* op = out + (bhN + (qf ? qg1 : qg0)) * DH;
#pragma unroll
    for (int db = 0; db < 4; db++) {
      float4 o;
      o.x = oacc[qf][db][0] * inv;
      o.y = oacc[qf][db][1] * inv;
      o.z = oacc[qf][db][2] * inv;
      o.w = oacc[qf][db][3] * inv;
      *(float4*)(op + db * 16 + 4 * g) = o;
    }
  }
}

extern "C" void kernel_launch(void* const* d_in, const int* in_sizes, int n_in,
                              void* d_out, int out_size, void* d_ws, size_t ws_size,
                              hipStream_t stream) {
  (void)in_sizes; (void)n_in; (void)out_size; (void)ws_size;
  const float* q = (const float*)d_in[0];
  const float* k = (const float*)d_in[1];
  const float* v = (const float*)d_in[2];
  float* out = (float*)d_out;

  // ws layout: K images 8 MiB | V images 8 MiB | bias 256 KiB
  char* ws = (char*)d_ws;
  unsigned short* wsK = (unsigned short*)ws;
  unsigned short* wsV = (unsigned short*)(ws + (8u << 20));
  float*          wsB = (float*)(ws + (16u << 20));

  build_ws<<<dim3(32, NT), dim3(256), 0, stream>>>(k, v, wsK, wsV, wsB);
  attend_l2_flash<<<dim3(2048), dim3(64), 0, stream>>>(q, wsK, wsV, wsB, out);
}

// Round 8
// 78.701 us; speedup vs baseline: 1.0983x; 1.0983x over previous
//
#include <hip/hip_runtime.h>

// L2-distance causal attention with zero-KV sink.
// B=2, H=16, N=2048, D=64. fp32 in/out, bf16 MFMA internally.
//
// Round 7: counted-vmcnt pipeline (T3/T4), 3 LDS buffers, 2-deep prefetch.
//   build_ws: per-64-key-tile images, K(slot-permuted, XOR-swizzled) and
//     V^T(transposed, XOR-swizzled) packed contiguously (16 KB/tile) + bias.
//   attend: QBLK=128 (4 waves x 32 queries), KVBLK=64. Per tile: one raw
//     s_barrier and one s_waitcnt vmcnt(4) — staging for tile t+2 stays in
//     flight across the barrier (never drains to 0). Issue order pinned with
//     sched_barrier(0): [bias(t) x4][STAGE(t+2) x4][QK][vmcnt(4)][softmax][PV].
//     FIFO retirement: vmcnt(4) certifies bias(t)+STAGE(t+1) done.
//   Grid: 512 blocks (2/CU, all resident), qt2 = y<8?15-y:y-8 pairs to
//     constant 34 kv-tiles per CU, heavy first; head pinned to XCD via b&31.

#define NQ 2048
#define DH 64
#define NT 32      // 64-key tiles per sequence
#define KVB 16384  // bytes per kv-tile image (K 8KB | V 8KB)

typedef float f32x4 __attribute__((ext_vector_type(4)));
typedef __bf16 bf16x8 __attribute__((ext_vector_type(8)));
typedef unsigned short u16x8 __attribute__((ext_vector_type(8)));

union B8 { u16x8 u; bf16x8 b; };

__device__ __forceinline__ unsigned short f2b(float f) {
  unsigned int x = __builtin_bit_cast(unsigned int, f);
  unsigned int r = x + 0x7fffu + ((x >> 16) & 1u);   // RNE to bf16
  return (unsigned short)(r >> 16);
}
__device__ __forceinline__ float b2f(unsigned short u) {
  unsigned int t = ((unsigned int)u) << 16;
  return __builtin_bit_cast(float, t);
}
__device__ __forceinline__ f32x4 vmax4(f32x4 a, f32x4 b) {
  f32x4 r;
  r[0] = fmaxf(a[0], b[0]); r[1] = fmaxf(a[1], b[1]);
  r[2] = fmaxf(a[2], b[2]); r[3] = fmaxf(a[3], b[3]);
  return r;
}

// K-slot permutation: slot s (bits c1 c0 g1 g0 r1 r0) holds key (c1 g1 g0 c0 r1 r0).
__device__ __forceinline__ int kslot(int a) {
  return (a & 0x23) | ((a & 0x04) << 2) | ((a & 0x18) >> 1);
}

__device__ __forceinline__ void gl_lds16(const void* g, void* l) {
  __builtin_amdgcn_global_load_lds(
      (const __attribute__((address_space(1))) unsigned int*)g,
      (__attribute__((address_space(3))) unsigned int*)l, 16, 0, 0);
}

constexpr float QS = 0.3551784733906239f;   // 2*log2(e)/sqrt(66)
constexpr float BS = 0.17758923669531197f;  // log2(e)/sqrt(66)

// ---------------- kernel 1: build per-tile images ----------------
__global__ __launch_bounds__(256) void build_ws(
    const float* __restrict__ k, const float* __restrict__ v,
    unsigned short* __restrict__ wsKV, float* __restrict__ wsB)
{
  const int bh = blockIdx.x;          // 0..31
  const int t  = blockIdx.y;          // 0..31
  const int tid  = threadIdx.x;
  const int wid  = tid >> 6;
  const int lane = tid & 63;
  const size_t bhN = (size_t)bh * NQ;
  const int tile64 = t * 64;
  const size_t tileId = (size_t)bh * NT + t;
  unsigned short* Kt = wsKV + tileId * 8192;   // 8 KB K image
  unsigned short* Vt = Kt + 4096;              // 8 KB V image
  float*          Bt = wsB + tileId * 64;

  // K image (+ bias), slot-permuted, XOR-swizzled — exact LDS byte image.
#pragma unroll
  for (int i = 0; i < 4; i++) {
    int f  = i * 256 + tid;
    int kg = f >> 4, d4 = f & 15;
    int slot = kslot(kg);
    const float4* kp = (const float4*)(k + (bhN + tile64 + kg) * DH);
    float4 kk = kp[d4];
    unsigned short h0 = f2b(kk.x), h1 = f2b(kk.y), h2 = f2b(kk.z), h3 = f2b(kk.w);
    float a0 = b2f(h0), a1 = b2f(h1), a2 = b2f(h2), a3 = b2f(h3);
    float ss = a0*a0 + a1*a1 + a2*a2 + a3*a3;     // |k_bf|^2 partial
    ss += __shfl_xor(ss, 1, 64);
    ss += __shfl_xor(ss, 2, 64);
    ss += __shfl_xor(ss, 4, 64);
    ss += __shfl_xor(ss, 8, 64);
    if (d4 == 0) Bt[slot] = -BS * ss;
    unsigned int w0 = (unsigned int)h0 | ((unsigned int)h1 << 16);
    unsigned int w1 = (unsigned int)h2 | ((unsigned int)h3 << 16);
    int idx = slot * 64 + ((d4 * 4) ^ ((slot & 7) << 3));
    uint2 wv; wv.x = w0; wv.y = w1;
    *(uint2*)&Kt[idx] = wv;
  }

  // V^T image (identity slot order), XOR-swizzled.
#pragma unroll
  for (int jj = 0; jj < 4; jj++) {
    int kgb = jj * 16 + wid * 4;
    const float* vp = v + (bhN + tile64 + kgb) * DH + lane;
    float x0 = vp[0], x1 = vp[DH], x2 = vp[2 * DH], x3 = vp[3 * DH];
    unsigned int w0 = (unsigned int)f2b(x0) | ((unsigned int)f2b(x1) << 16);
    unsigned int w1 = (unsigned int)f2b(x2) | ((unsigned int)f2b(x3) << 16);
    int idx = lane * 64 + (kgb ^ ((lane & 7) << 3));
    uint2 wv; wv.x = w0; wv.y = w1;
    *(uint2*)&Vt[idx] = wv;
  }
}

// ---------------- kernel 2: counted-vmcnt flash attention ----------------
__global__ __launch_bounds__(256) void attend_l2_flash(
    const float* __restrict__ q,
    const unsigned short* __restrict__ wsKV,
    const float* __restrict__ wsB,
    float* __restrict__ out)
{
  const int b    = blockIdx.x;        // 512 blocks, 2/CU, all resident
  const int bh   = b & 31;            // head pinned to one XCD's L2
  const int y    = b >> 5;            // 0..15
  const int qt2  = (y < 8) ? (15 - y) : (y - 8);   // pair-balanced, heavy first
  const int ntiles = 2 * qt2 + 2;

  const int tid  = threadIdx.x;       // 0..255
  const int wid  = tid >> 6;
  const int lane = tid & 63;
  const int g    = lane >> 4;
  const int qi   = lane & 15;
  const int qg0  = qt2 * 128 + wid * 32 + qi;   // fragment qf=0 query row
  const int qg1  = qg0 + 16;                    // fragment qf=1 query row
  const size_t bhN = (size_t)bh * NQ;

  __shared__ __align__(16) unsigned short u[3][8192];  // 3 x 16 KB KV buffers

  // ---- Q fragments (hi/lo split), both qf, hoisted (loads issued first) ----
  bf16x8 qhi[2][2], qlo[2][2];   // [qf][ks]
#pragma unroll
  for (int qf = 0; qf < 2; qf++) {
    const float* qrow = q + (bhN + (qf ? qg1 : qg0)) * DH;
#pragma unroll
    for (int ks = 0; ks < 2; ks++) {
      B8 th, tl;
#pragma unroll
      for (int j = 0; j < 8; j++) {
        float x = qrow[ks * 32 + g * 8 + j] * QS;
        unsigned short h = f2b(x);
        th.u[j] = h;
        tl.u[j] = f2b(x - b2f(h));
      }
      qhi[qf][ks] = th.b; qlo[qf][ks] = tl.b;
    }
  }

  f32x4 oacc[2][4] = {};          // [qf][db], O^T accumulators
  float m[2] = {0.0f, 0.0f};      // running max per fragment (sink pins >= 0)
  f32x4 l4[2] = {{0,0,0,0},{0,0,0,0}};

  const char*  KV0 = (const char*)wsKV + (size_t)bh * NT * KVB;
  const float* Bp0 = wsB + (size_t)bh * NT * 64;

  // stage kv-tile tt into buf: pure linear DMA, 4 VMEM instr per wave
  auto STAGE = [&](unsigned short* buf, int tt) {
    const char* src = KV0 + (size_t)tt * KVB;
#pragma unroll
    for (int cc = 0; cc < 4; cc++)
      gl_lds16(src + cc * 4096 + tid * 16, (char*)buf + cc * 4096 + tid * 16);
  };

  unsigned short *pA = u[0], *pB = u[1], *pC = u[2];
  STAGE(pA, 0);
  STAGE(pB, 1);
  asm volatile("s_waitcnt vmcnt(4)" ::: "memory");   // STAGE(0) done; (1) in flight
  __builtin_amdgcn_sched_barrier(0);
  __builtin_amdgcn_s_barrier();

  for (int t = 0; t < ntiles; t++) {
    // ---- bias(t) -> regs (4 VMEM, issued BEFORE the stage ops) ----
    const float* bp = Bp0 + t * 64;
    f32x4 bb[4];
#pragma unroll
    for (int c = 0; c < 4; c++) bb[c] = *(const f32x4*)(bp + 16 * c + 4 * g);
    __builtin_amdgcn_sched_barrier(0);

    // ---- STAGE(t+2) into pC (clamped at tail: harmless dup, uniform count) ----
    int ts = (t + 2 < ntiles) ? (t + 2) : (ntiles - 1);
    STAGE(pC, ts);
    __builtin_amdgcn_sched_barrier(0);

    // ---- QK^T from pA, swapped: S^T = K . Q^T ----
    f32x4 sc[2][4] = {};
#pragma unroll
    for (int c = 0; c < 4; c++) {
#pragma unroll
      for (int ks = 0; ks < 2; ks++) {
        int idx = (16 * c + qi) * 64 + ((ks * 32 + g * 8) ^ ((qi & 7) << 3));
        bf16x8 ak = *(const bf16x8*)&pA[idx];
        sc[0][c] = __builtin_amdgcn_mfma_f32_16x16x32_bf16(ak, qhi[0][ks], sc[0][c], 0, 0, 0);
        sc[0][c] = __builtin_amdgcn_mfma_f32_16x16x32_bf16(ak, qlo[0][ks], sc[0][c], 0, 0, 0);
        sc[1][c] = __builtin_amdgcn_mfma_f32_16x16x32_bf16(ak, qhi[1][ks], sc[1][c], 0, 0, 0);
        sc[1][c] = __builtin_amdgcn_mfma_f32_16x16x32_bf16(ak, qlo[1][ks], sc[1][c], 0, 0, 0);
      }
    }

    // ---- counted wait: bias(t)+STAGE(t+1) done; STAGE(t+2) stays in flight ----
    asm volatile("s_waitcnt vmcnt(4)" ::: "memory");
    __builtin_amdgcn_sched_barrier(0);

    // ---- softmax: s = sc + bias, causal mask on the last TWO tiles ----
    const bool diag = (t >= ntiles - 2);
    const int tile64 = t * 64;
#pragma unroll
    for (int c = 0; c < 4; c++) {
      sc[0][c] += bb[c];                        // v_pk_add_f32
      sc[1][c] += bb[c];
      if (diag) {
#pragma unroll
        for (int r = 0; r < 4; r++) {
          int key = tile64 + 32 * (c >> 1) + 8 * g + 4 * (c & 1) + r; // pi(slot)
          if (key > qg0) sc[0][c][r] = -1e30f;
          if (key > qg1) sc[1][c][r] = -1e30f;
        }
      }
    }

    // ---- exact defer-max (both fragments; ~never fires, sink pins m=0) ----
    f32x4 mv0 = vmax4(vmax4(sc[0][0], sc[0][1]), vmax4(sc[0][2], sc[0][3]));
    f32x4 mv1 = vmax4(vmax4(sc[1][0], sc[1][1]), vmax4(sc[1][2], sc[1][3]));
    float ml0 = fmaxf(fmaxf(fmaxf(mv0[0], mv0[1]), mv0[2]), mv0[3]);
    float ml1 = fmaxf(fmaxf(fmaxf(mv1[0], mv1[1]), mv1[2]), mv1[3]);
    if (!__all((ml0 <= m[0]) && (ml1 <= m[1]))) {
      float mt0 = fmaxf(ml0, __shfl_xor(ml0, 16, 64));
      mt0 = fmaxf(mt0, __shfl_xor(mt0, 32, 64));
      float dm0 = fmaxf(mt0 - m[0], 0.0f);
      m[0] += dm0;
      float a0 = exp2f(-dm0);
      l4[0] *= a0;
#pragma unroll
      for (int db = 0; db < 4; db++) oacc[0][db] *= a0;
      float mt1 = fmaxf(ml1, __shfl_xor(ml1, 16, 64));
      mt1 = fmaxf(mt1, __shfl_xor(mt1, 32, 64));
      float dm1 = fmaxf(mt1 - m[1], 0.0f);
      m[1] += dm1;
      float a1 = exp2f(-dm1);
      l4[1] *= a1;
#pragma unroll
      for (int db = 0; db < 4; db++) oacc[1][db] *= a1;
    }

    // ---- weights: e = exp2(s - m); m==0 fast path skips the subtract ----
    if (__all((m[0] == 0.0f) && (m[1] == 0.0f))) {
#pragma unroll
      for (int c = 0; c < 4; c++) {
#pragma unroll
        for (int r = 0; r < 4; r++) {
          sc[0][c][r] = exp2f(sc[0][c][r]);
          sc[1][c][r] = exp2f(sc[1][c][r]);
        }
        l4[0] += sc[0][c];
        l4[1] += sc[1][c];
      }
    } else {
#pragma unroll
      for (int c = 0; c < 4; c++) {
#pragma unroll
        for (int r = 0; r < 4; r++) {
          sc[0][c][r] = exp2f(sc[0][c][r] - m[0]);
          sc[1][c][r] = exp2f(sc[1][c][r] - m[1]);
        }
        l4[0] += sc[0][c];
        l4[1] += sc[1][c];
      }
    }

    // ---- P repack (local by slot-permutation construction) ----
    B8 pr[2][2];
#pragma unroll
    for (int qf = 0; qf < 2; qf++)
#pragma unroll
      for (int j = 0; j < 8; j++) {
        pr[qf][0].b[j] = (__bf16)sc[qf][(j >> 2)][j & 3];
        pr[qf][1].b[j] = (__bf16)sc[qf][2 + (j >> 2)][j & 3];
      }

    // ---- PV from pA+4096: O^T += V^T . P^T ----
#pragma unroll
    for (int db = 0; db < 4; db++) {
#pragma unroll
      for (int ks = 0; ks < 2; ks++) {
        int idx = 4096 + (db * 16 + qi) * 64 + ((ks * 32 + g * 8) ^ ((qi & 7) << 3));
        bf16x8 av = *(const bf16x8*)&pA[idx];
        oacc[0][db] = __builtin_amdgcn_mfma_f32_16x16x32_bf16(av, pr[0][ks].b, oacc[0][db], 0, 0, 0);
        oacc[1][db] = __builtin_amdgcn_mfma_f32_16x16x32_bf16(av, pr[1][ks].b, oacc[1][db], 0, 0, 0);
      }
    }

    __builtin_amdgcn_s_barrier();   // raw barrier: no vmcnt drain
    // rotate buffers: next tile computes pB, stages into old pA
    unsigned short* tp = pA; pA = pB; pB = pC; pC = tp;
  }

  // ---- epilogue (both fragments) ----
#pragma unroll
  for (int qf = 0; qf < 2; qf++) {
    float lt = (l4[qf][0] + l4[qf][1]) + (l4[qf][2] + l4[qf][3]);
    lt += __shfl_xor(lt, 16, 64);
    lt += __shfl_xor(lt, 32, 64);
    float denom = lt + exp2f(-m[qf]);   // + sink weight
    float inv = 1.0f / denom;
    float* op = out + (bhN + (qf ? qg1 : qg0)) * DH;
#pragma unroll
    for (int db = 0; db < 4; db++) {
      float4 o;
      o.x = oacc[qf][db][0] * inv;
      o.y = oacc[qf][db][1] * inv;
      o.z = oacc[qf][db][2] * inv;
      o.w = oacc[qf][db][3] * inv;
      *(float4*)(op + db * 16 + 4 * g) = o;
    }
  }
}

extern "C" void kernel_launch(void* const* d_in, const int* in_sizes, int n_in,
                              void* d_out, int out_size, void* d_ws, size_t ws_size,
                              hipStream_t stream) {
  (void)in_sizes; (void)n_in; (void)out_size; (void)ws_size;
  const float* q = (const float*)d_in[0];
  const float* k = (const float*)d_in[1];
  const float* v = (const float*)d_in[2];
  float* out = (float*)d_out;

  // ws layout: KV images 16 MiB | bias 256 KiB
  char* ws = (char*)d_ws;
  unsigned short* wsKV = (unsigned short*)ws;
  float*          wsB  = (float*)(ws + (16u << 20));

  build_ws<<<dim3(32, NT), dim3(256), 0, stream>>>(k, v, wsKV, wsB);
  attend_l2_flash<<<dim3(512), dim3(256), 0, stream>>>(q, wsKV, wsB, out);
}

// Round 10
// 59.216 us; speedup vs baseline: 1.4597x; 1.3290x over previous
//
#include <hip/hip_runtime.h>

// L2-distance causal attention with zero-KV sink.
// B=2, H=16, N=2048, D=64. fp32 in/out, bf16 MFMA internally.
//
// Structure (= round-2 winner + single-pass bf16 Q):
//   Kernel 1 (build_ws): one-shot conversion of K/V into per-tile LDS byte
//     images (bf16, slot-permuted + XOR-swizzled K; transposed + swizzled V^T)
//     plus the per-key bias -BS*|k_bf|^2, stored in d_ws.
//   Kernel 2 (attend): flash loop; stages each tile image with
//     global_load_lds width=16 (linear copy), double-buffered, one barrier
//     per tile. Softmax fully in-register via swapped QK^T + slot permutation.
//     Round 9: Q is a SINGLE bf16 pass (hi/lo split dropped — Q-rounding adds
//     ~0.2% relative weight noise, far under threshold). QK MFMAs halve
//     (24 -> 16 MFMA per wave-tile), chain depth halves, VGPR drops.

#define NQ 2048
#define DH 64
#define NT 32   // KV tiles per sequence (2048/64)

typedef float f32x4 __attribute__((ext_vector_type(4)));
typedef __bf16 bf16x8 __attribute__((ext_vector_type(8)));
typedef unsigned short u16x8 __attribute__((ext_vector_type(8)));

union B8 { u16x8 u; bf16x8 b; };

__device__ __forceinline__ unsigned short f2b(float f) {
  unsigned int x = __builtin_bit_cast(unsigned int, f);
  unsigned int r = x + 0x7fffu + ((x >> 16) & 1u);   // RNE to bf16
  return (unsigned short)(r >> 16);
}
__device__ __forceinline__ float b2f(unsigned short u) {
  unsigned int t = ((unsigned int)u) << 16;
  return __builtin_bit_cast(float, t);
}
__device__ __forceinline__ f32x4 vmax4(f32x4 a, f32x4 b) {
  f32x4 r;
  r[0] = fmaxf(a[0], b[0]); r[1] = fmaxf(a[1], b[1]);
  r[2] = fmaxf(a[2], b[2]); r[3] = fmaxf(a[3], b[3]);
  return r;
}

// K-slot permutation: slot s (bits c1 c0 g1 g0 r1 r0) holds key (c1 g1 g0 c0 r1 r0).
// Makes QK^T's C-layout scores be exactly the PV B-fragment values (no exchange).
__device__ __forceinline__ int kslot(int a) {
  return (a & 0x23) | ((a & 0x04) << 2) | ((a & 0x18) >> 1);
}

__device__ __forceinline__ void gl_lds16(const void* g, void* l) {
  __builtin_amdgcn_global_load_lds(
      (const __attribute__((address_space(1))) unsigned int*)g,
      (__attribute__((address_space(3))) unsigned int*)l, 16, 0, 0);
}
__device__ __forceinline__ void gl_lds4(const void* g, void* l) {
  __builtin_amdgcn_global_load_lds(
      (const __attribute__((address_space(1))) unsigned int*)g,
      (__attribute__((address_space(3))) unsigned int*)l, 4, 0, 0);
}

constexpr float QS = 0.3551784733906239f;   // 2*log2(e)/sqrt(66)
constexpr float BS = 0.17758923669531197f;  // log2(e)/sqrt(66)

// ---------------- kernel 1: build per-tile images ----------------
__global__ __launch_bounds__(256) void build_ws(
    const float* __restrict__ k, const float* __restrict__ v,
    unsigned short* __restrict__ wsK, unsigned short* __restrict__ wsV,
    float* __restrict__ wsB)
{
  const int bh = blockIdx.x;          // 0..31
  const int t  = blockIdx.y;          // 0..31
  const int tid  = threadIdx.x;
  const int wid  = tid >> 6;
  const int lane = tid & 63;
  const size_t bhN = (size_t)bh * NQ;
  const int tile64 = t * 64;
  const size_t tileId = (size_t)bh * NT + t;
  unsigned short* Kt = wsK + tileId * 4096;
  unsigned short* Vt = wsV + tileId * 4096;
  float*          Bt = wsB + tileId * 64;

  // K image (+ bias), slot-permuted, XOR-swizzled — exact LDS byte image.
#pragma unroll
  for (int i = 0; i < 4; i++) {
    int f  = i * 256 + tid;
    int kg = f >> 4, d4 = f & 15;
    int slot = kslot(kg);
    const float4* kp = (const float4*)(k + (bhN + tile64 + kg) * DH);
    float4 kk = kp[d4];
    unsigned short h0 = f2b(kk.x), h1 = f2b(kk.y), h2 = f2b(kk.z), h3 = f2b(kk.w);
    float a0 = b2f(h0), a1 = b2f(h1), a2 = b2f(h2), a3 = b2f(h3);
    float ss = a0*a0 + a1*a1 + a2*a2 + a3*a3;     // |k_bf|^2 partial
    ss += __shfl_xor(ss, 1, 64);
    ss += __shfl_xor(ss, 2, 64);
    ss += __shfl_xor(ss, 4, 64);
    ss += __shfl_xor(ss, 8, 64);
    if (d4 == 0) Bt[slot] = -BS * ss;
    unsigned int w0 = (unsigned int)h0 | ((unsigned int)h1 << 16);
    unsigned int w1 = (unsigned int)h2 | ((unsigned int)h3 << 16);
    int idx = slot * 64 + ((d4 * 4) ^ ((slot & 7) << 3));
    uint2 wv; wv.x = w0; wv.y = w1;
    *(uint2*)&Kt[idx] = wv;
  }

  // V^T image (identity slot order), XOR-swizzled.
#pragma unroll
  for (int jj = 0; jj < 4; jj++) {
    int kgb = jj * 16 + wid * 4;
    const float* vp = v + (bhN + tile64 + kgb) * DH + lane;
    float x0 = vp[0], x1 = vp[DH], x2 = vp[2 * DH], x3 = vp[3 * DH];
    unsigned int w0 = (unsigned int)f2b(x0) | ((unsigned int)f2b(x1) << 16);
    unsigned int w1 = (unsigned int)f2b(x2) | ((unsigned int)f2b(x3) << 16);
    int idx = lane * 64 + (kgb ^ ((lane & 7) << 3));
    uint2 wv; wv.x = w0; wv.y = w1;
    *(uint2*)&Vt[idx] = wv;
  }
}

// ---------------- kernel 2: flash attention over premade images ----------------
__global__ __launch_bounds__(256) void attend_l2_flash(
    const float* __restrict__ q,
    const unsigned short* __restrict__ wsK,
    const unsigned short* __restrict__ wsV,
    const float* __restrict__ wsB,
    float* __restrict__ out)
{
  const int bh   = blockIdx.x;
  const int qt   = (gridDim.y - 1) - blockIdx.y;   // heavy tiles dispatch first
  const int qbase = qt * 64;
  const int tid  = threadIdx.x;
  const int wid  = tid >> 6;
  const int lane = tid & 63;
  const int g    = lane >> 4;
  const int qi   = lane & 15;
  const int qg   = qbase + wid * 16 + qi;          // this lane's query row
  const size_t bhN = (size_t)bh * NQ;

  __shared__ __align__(16) unsigned short sK[2][4096];
  __shared__ __align__(16) unsigned short sV[2][4096];
  __shared__ __align__(16) float sB[2][64];

  // ---- Q fragments (single bf16 pass), hoisted ----
  const float* qrow = q + (bhN + qg) * DH;
  bf16x8 q8[2];
#pragma unroll
  for (int ks = 0; ks < 2; ks++) {
    B8 th;
#pragma unroll
    for (int j = 0; j < 8; j++)
      th.u[j] = f2b(qrow[ks * 32 + g * 8 + j] * QS);
    q8[ks] = th.b;
  }

  f32x4 oacc[4] = { {0,0,0,0}, {0,0,0,0}, {0,0,0,0}, {0,0,0,0} };
  float m = 0.0f;                 // running max (base-2; sink pins m >= 0)
  f32x4 l4 = {0, 0, 0, 0};        // packed partial denominator

  const int ntiles = qt + 1;
  const size_t tbase = (size_t)bh * NT;

  auto STAGE = [&](int buf, int t) {
    const char* Kt = (const char*)(wsK + (tbase + t) * 4096);
    const char* Vt = (const char*)(wsV + (tbase + t) * 4096);
#pragma unroll
    for (int c = 0; c < 2; c++) {
      int boff = wid * 2048 + c * 1024;
      gl_lds16(Kt + boff + lane * 16, (char*)&sK[buf][0] + boff);
      gl_lds16(Vt + boff + lane * 16, (char*)&sV[buf][0] + boff);
    }
    if (wid == 0) {
      const char* Bt = (const char*)(wsB + (tbase + t) * 64);
      gl_lds4(Bt + lane * 4, (char*)&sB[buf][0]);
    }
  };

  int cur = 0;
  STAGE(0, 0);
  __syncthreads();

  for (int t = 0; t < ntiles; t++) {
    if (t + 1 < ntiles) STAGE(cur ^ 1, t + 1);

    // ---- QK^T, swapped: S^T = K . Q^T (8 MFMA) ----
    f32x4 sc[4] = { {0,0,0,0}, {0,0,0,0}, {0,0,0,0}, {0,0,0,0} };
#pragma unroll
    for (int c = 0; c < 4; c++) {
#pragma unroll
      for (int ks = 0; ks < 2; ks++) {
        int idx = (16 * c + qi) * 64 + ((ks * 32 + g * 8) ^ ((qi & 7) << 3));
        bf16x8 ak = *(const bf16x8*)&sK[cur][idx];
        sc[c] = __builtin_amdgcn_mfma_f32_16x16x32_bf16(ak, q8[ks], sc[c], 0, 0, 0);
      }
    }

    // ---- softmax: s = sc + bias, causal mask on diag tile ----
    const bool diag = (t == ntiles - 1);
    const int tile64 = t * 64;
#pragma unroll
    for (int c = 0; c < 4; c++) {
      f32x4 bb = *(const f32x4*)&sB[cur][16 * c + 4 * g];
      sc[c] += bb;                              // v_pk_add_f32
      if (diag) {
#pragma unroll
        for (int r = 0; r < 4; r++) {
          int key = tile64 + 32 * (c >> 1) + 8 * g + 4 * (c & 1) + r; // pi(slot)
          if (key > qg) sc[c][r] = -1e30f;
        }
      }
    }

    // ---- exact defer-max: rescale only if some score exceeds running max ----
    f32x4 mv = vmax4(vmax4(sc[0], sc[1]), vmax4(sc[2], sc[3]));
    float mloc = fmaxf(fmaxf(fmaxf(mv[0], mv[1]), mv[2]), mv[3]); // v_max3 fuse
    if (!__all(mloc <= m)) {                    // ~never taken (sink pins m=0)
      float mt = fmaxf(mloc, __shfl_xor(mloc, 16, 64));
      mt = fmaxf(mt, __shfl_xor(mt, 32, 64));
      float dm = fmaxf(mt - m, 0.0f);           // per-query, exact
      m += dm;
      float alpha = exp2f(-dm);
      l4 *= alpha;
#pragma unroll
      for (int db = 0; db < 4; db++) oacc[db] *= alpha;
    }

    // ---- weights: e = exp2(s - m); m==0 fast path skips the subtract ----
    if (__all(m == 0.0f)) {
#pragma unroll
      for (int c = 0; c < 4; c++) {
#pragma unroll
        for (int r = 0; r < 4; r++) sc[c][r] = exp2f(sc[c][r]);
        l4 += sc[c];
      }
    } else {
#pragma unroll
      for (int c = 0; c < 4; c++) {
#pragma unroll
        for (int r = 0; r < 4; r++) sc[c][r] = exp2f(sc[c][r] - m);
        l4 += sc[c];
      }
    }

    // ---- P repack (local by slot-permutation construction) ----
    B8 t0, t1;
#pragma unroll
    for (int j = 0; j < 8; j++) {
      t0.b[j] = (__bf16)sc[(j >> 2)][j & 3];
      t1.b[j] = (__bf16)sc[2 + (j >> 2)][j & 3];
    }

    // ---- PV: O^T += V^T . P^T ----
#pragma unroll
    for (int db = 0; db < 4; db++) {
#pragma unroll
      for (int ks = 0; ks < 2; ks++) {
        int idx = (db * 16 + qi) * 64 + ((ks * 32 + g * 8) ^ ((qi & 7) << 3));
        bf16x8 av = *(const bf16x8*)&sV[cur][idx];
        oacc[db] = __builtin_amdgcn_mfma_f32_16x16x32_bf16(av, (ks ? t1.b : t0.b),
                                                           oacc[db], 0, 0, 0);
      }
    }
    __syncthreads();   // drains vmcnt (next tile landed) + LDS-read reuse fence
    cur ^= 1;
  }

  // ---- epilogue ----
  float lt = (l4[0] + l4[1]) + (l4[2] + l4[3]);
  lt += __shfl_xor(lt, 16, 64);
  lt += __shfl_xor(lt, 32, 64);
  float denom = lt + exp2f(-m);   // + sink weight
  float inv = 1.0f / denom;
  float* op = out + (bhN + qg) * DH;
#pragma unroll
  for (int db = 0; db < 4; db++) {
    float4 o;
    o.x = oacc[db][0] * inv;
    o.y = oacc[db][1] * inv;
    o.z = oacc[db][2] * inv;
    o.w = oacc[db][3] * inv;
    *(float4*)(op + db * 16 + 4 * g) = o;
  }
}

extern "C" void kernel_launch(void* const* d_in, const int* in_sizes, int n_in,
                              void* d_out, int out_size, void* d_ws, size_t ws_size,
                              hipStream_t stream) {
  (void)in_sizes; (void)n_in; (void)out_size; (void)ws_size;
  const float* q = (const float*)d_in[0];
  const float* k = (const float*)d_in[1];
  const float* v = (const float*)d_in[2];
  float* out = (float*)d_out;

  // ws layout: K images 8 MiB | V images 8 MiB | bias 256 KiB
  char* ws = (char*)d_ws;
  unsigned short* wsK = (unsigned short*)ws;
  unsigned short* wsV = (unsigned short*)(ws + (8u << 20));
  float*          wsB = (float*)(ws + (16u << 20));

  build_ws<<<dim3(32, NT), dim3(256), 0, stream>>>(k, v, wsK, wsV, wsB);
  attend_l2_flash<<<dim3(32, NT), dim3(256), 0, stream>>>(q, wsK, wsV, wsB, out);
}

// Round 11
// 52.608 us; speedup vs baseline: 1.6431x; 1.1256x over previous
//
#include <hip/hip_runtime.h>

// L2-distance causal attention with zero-KV sink.
// B=2, H=16, N=2048, D=64. fp32 in/out, bf16 MFMA internally.
//
// Round 10: NO online-softmax machinery at all.
//   Sink pins the reference max at 0 and |s| <= ~21 log2-units, so f32
//   exp2(s) never overflows -> no running max, no rescale, ever.
//   The per-key bias b_j = -BS*|k_bf|^2 is folded at build time:
//     V image holds v'_j = 2^{b_j} * v_j   (bf16)
//     tb image holds 2^{b_j}               (f32, slot-permuted)
//   Per tile: p = exp2(s_raw);  O += p.V' (MFMA);  l += p*tb (pk-fma).
//   Output = O / (l + 1)  — identical math, new chain: QK -> exp2 -> PV.
//
//   Kernel 1 (build_ws): per-64-key-tile images (K slot-permuted+XOR-swizzled,
//     V^T transposed+XOR-swizzled+2^b-scaled) + tb vector.
//   Kernel 2 (attend): flash loop, double-buffered global_load_lds staging,
//     one barrier per tile, grid (32,32) heavy-first. Single bf16 Q pass.

#define NQ 2048
#define DH 64
#define NT 32   // KV tiles per sequence (2048/64)

typedef float f32x4 __attribute__((ext_vector_type(4)));
typedef __bf16 bf16x8 __attribute__((ext_vector_type(8)));
typedef unsigned short u16x8 __attribute__((ext_vector_type(8)));

union B8 { u16x8 u; bf16x8 b; };

__device__ __forceinline__ unsigned short f2b(float f) {
  unsigned int x = __builtin_bit_cast(unsigned int, f);
  unsigned int r = x + 0x7fffu + ((x >> 16) & 1u);   // RNE to bf16
  return (unsigned short)(r >> 16);
}
__device__ __forceinline__ float b2f(unsigned short u) {
  unsigned int t = ((unsigned int)u) << 16;
  return __builtin_bit_cast(float, t);
}

// K-slot permutation: slot s (bits c1 c0 g1 g0 r1 r0) holds key (c1 g1 g0 c0 r1 r0).
// Makes QK^T's C-layout scores be exactly the PV B-fragment values (no exchange).
__device__ __forceinline__ int kslot(int a) {
  return (a & 0x23) | ((a & 0x04) << 2) | ((a & 0x18) >> 1);
}

__device__ __forceinline__ void gl_lds16(const void* g, void* l) {
  __builtin_amdgcn_global_load_lds(
      (const __attribute__((address_space(1))) unsigned int*)g,
      (__attribute__((address_space(3))) unsigned int*)l, 16, 0, 0);
}
__device__ __forceinline__ void gl_lds4(const void* g, void* l) {
  __builtin_amdgcn_global_load_lds(
      (const __attribute__((address_space(1))) unsigned int*)g,
      (__attribute__((address_space(3))) unsigned int*)l, 4, 0, 0);
}

constexpr float QS = 0.3551784733906239f;   // 2*log2(e)/sqrt(66)
constexpr float BS = 0.17758923669531197f;  // log2(e)/sqrt(66)

// ---------------- kernel 1: build per-tile images ----------------
__global__ __launch_bounds__(256) void build_ws(
    const float* __restrict__ k, const float* __restrict__ v,
    unsigned short* __restrict__ wsK, unsigned short* __restrict__ wsV,
    float* __restrict__ wsB)
{
  const int bh = blockIdx.x;          // 0..31
  const int t  = blockIdx.y;          // 0..31
  const int tid  = threadIdx.x;
  const int wid  = tid >> 6;
  const int lane = tid & 63;
  const size_t bhN = (size_t)bh * NQ;
  const int tile64 = t * 64;
  const size_t tileId = (size_t)bh * NT + t;
  unsigned short* Kt = wsK + tileId * 4096;
  unsigned short* Vt = wsV + tileId * 4096;
  float*          Bt = wsB + tileId * 64;

  __shared__ float sTb[64];   // 2^{b_j} by KEY index (for the V pass)

  // K image (+ tb), slot-permuted, XOR-swizzled — exact LDS byte image.
#pragma unroll
  for (int i = 0; i < 4; i++) {
    int f  = i * 256 + tid;
    int kg = f >> 4, d4 = f & 15;
    int slot = kslot(kg);
    const float4* kp = (const float4*)(k + (bhN + tile64 + kg) * DH);
    float4 kk = kp[d4];
    unsigned short h0 = f2b(kk.x), h1 = f2b(kk.y), h2 = f2b(kk.z), h3 = f2b(kk.w);
    float a0 = b2f(h0), a1 = b2f(h1), a2 = b2f(h2), a3 = b2f(h3);
    float ss = a0*a0 + a1*a1 + a2*a2 + a3*a3;     // |k_bf|^2 partial
    ss += __shfl_xor(ss, 1, 64);
    ss += __shfl_xor(ss, 2, 64);
    ss += __shfl_xor(ss, 4, 64);
    ss += __shfl_xor(ss, 8, 64);
    if (d4 == 0) {
      float tb = __builtin_amdgcn_exp2f(-BS * ss);  // 2^{bias}
      Bt[slot] = tb;       // slot-permuted image for the attend kernel
      sTb[kg]  = tb;       // key-indexed for the V pass below
    }
    unsigned int w0 = (unsigned int)h0 | ((unsigned int)h1 << 16);
    unsigned int w1 = (unsigned int)h2 | ((unsigned int)h3 << 16);
    int idx = slot * 64 + ((d4 * 4) ^ ((slot & 7) << 3));
    uint2 wv; wv.x = w0; wv.y = w1;
    *(uint2*)&Kt[idx] = wv;
  }
  __syncthreads();

  // V^T image (identity slot order), XOR-swizzled, pre-scaled by 2^{b_j}.
#pragma unroll
  for (int jj = 0; jj < 4; jj++) {
    int kgb = jj * 16 + wid * 4;
    const float* vp = v + (bhN + tile64 + kgb) * DH + lane;
    float x0 = vp[0] * sTb[kgb + 0];
    float x1 = vp[DH] * sTb[kgb + 1];
    float x2 = vp[2 * DH] * sTb[kgb + 2];
    float x3 = vp[3 * DH] * sTb[kgb + 3];
    unsigned int w0 = (unsigned int)f2b(x0) | ((unsigned int)f2b(x1) << 16);
    unsigned int w1 = (unsigned int)f2b(x2) | ((unsigned int)f2b(x3) << 16);
    int idx = lane * 64 + (kgb ^ ((lane & 7) << 3));
    uint2 wv; wv.x = w0; wv.y = w1;
    *(uint2*)&Vt[idx] = wv;
  }
}

// ---------------- kernel 2: flash attention over premade images ----------------
__global__ __launch_bounds__(256) void attend_l2_flash(
    const float* __restrict__ q,
    const unsigned short* __restrict__ wsK,
    const unsigned short* __restrict__ wsV,
    const float* __restrict__ wsB,
    float* __restrict__ out)
{
  const int bh   = blockIdx.x;
  const int qt   = (gridDim.y - 1) - blockIdx.y;   // heavy tiles dispatch first
  const int qbase = qt * 64;
  const int tid  = threadIdx.x;
  const int wid  = tid >> 6;
  const int lane = tid & 63;
  const int g    = lane >> 4;
  const int qi   = lane & 15;
  const int qg   = qbase + wid * 16 + qi;          // this lane's query row
  const size_t bhN = (size_t)bh * NQ;

  __shared__ __align__(16) unsigned short sK[2][4096];
  __shared__ __align__(16) unsigned short sV[2][4096];
  __shared__ __align__(16) float sB[2][64];        // tb = 2^{bias}, slot-permuted

  // ---- Q fragments (single bf16 pass), hoisted ----
  const float* qrow = q + (bhN + qg) * DH;
  bf16x8 q8[2];
#pragma unroll
  for (int ks = 0; ks < 2; ks++) {
    B8 th;
#pragma unroll
    for (int j = 0; j < 8; j++)
      th.u[j] = f2b(qrow[ks * 32 + g * 8 + j] * QS);
    q8[ks] = th.b;
  }

  f32x4 oacc[4] = { {0,0,0,0}, {0,0,0,0}, {0,0,0,0}, {0,0,0,0} };
  f32x4 l4 = {0, 0, 0, 0};        // packed partial denominator

  const int ntiles = qt + 1;
  const size_t tbase = (size_t)bh * NT;

  auto STAGE = [&](int buf, int t) {
    const char* Kt = (const char*)(wsK + (tbase + t) * 4096);
    const char* Vt = (const char*)(wsV + (tbase + t) * 4096);
#pragma unroll
    for (int c = 0; c < 2; c++) {
      int boff = wid * 2048 + c * 1024;
      gl_lds16(Kt + boff + lane * 16, (char*)&sK[buf][0] + boff);
      gl_lds16(Vt + boff + lane * 16, (char*)&sV[buf][0] + boff);
    }
    if (wid == 0) {
      const char* Bt = (const char*)(wsB + (tbase + t) * 64);
      gl_lds4(Bt + lane * 4, (char*)&sB[buf][0]);
    }
  };

  int cur = 0;
  STAGE(0, 0);
  __syncthreads();

  for (int t = 0; t < ntiles; t++) {
    if (t + 1 < ntiles) STAGE(cur ^ 1, t + 1);

    // ---- QK^T, swapped: S^T = K . Q^T (8 MFMA) ----
    f32x4 sc[4] = { {0,0,0,0}, {0,0,0,0}, {0,0,0,0}, {0,0,0,0} };
#pragma unroll
    for (int c = 0; c < 4; c++) {
#pragma unroll
      for (int ks = 0; ks < 2; ks++) {
        int idx = (16 * c + qi) * 64 + ((ks * 32 + g * 8) ^ ((qi & 7) << 3));
        bf16x8 ak = *(const bf16x8*)&sK[cur][idx];
        sc[c] = __builtin_amdgcn_mfma_f32_16x16x32_bf16(ak, q8[ks], sc[c], 0, 0, 0);
      }
    }

    // ---- causal mask on diag tile (masked -> exp2 gives exactly 0) ----
    const bool diag = (t == ntiles - 1);
    if (diag) {
      const int tile64 = t * 64;
#pragma unroll
      for (int c = 0; c < 4; c++)
#pragma unroll
        for (int r = 0; r < 4; r++) {
          int key = tile64 + 32 * (c >> 1) + 8 * g + 4 * (c & 1) + r; // pi(slot)
          if (key > qg) sc[c][r] = -1e30f;
        }
    }

    // ---- weights: p = exp2(s_raw); l += p * tb  (no max, no rescale) ----
#pragma unroll
    for (int c = 0; c < 4; c++) {
      f32x4 tb = *(const f32x4*)&sB[cur][16 * c + 4 * g];
#pragma unroll
      for (int r = 0; r < 4; r++) sc[c][r] = __builtin_amdgcn_exp2f(sc[c][r]);
#pragma unroll
      for (int r = 0; r < 4; r++) l4[r] = __builtin_fmaf(sc[c][r], tb[r], l4[r]);
    }

    // ---- P repack (local by slot-permutation construction) ----
    B8 t0, t1;
#pragma unroll
    for (int j = 0; j < 8; j++) {
      t0.b[j] = (__bf16)sc[(j >> 2)][j & 3];
      t1.b[j] = (__bf16)sc[2 + (j >> 2)][j & 3];
    }

    // ---- PV: O^T += V'^T . P^T  (bias folded into V') ----
#pragma unroll
    for (int db = 0; db < 4; db++) {
#pragma unroll
      for (int ks = 0; ks < 2; ks++) {
        int idx = (db * 16 + qi) * 64 + ((ks * 32 + g * 8) ^ ((qi & 7) << 3));
        bf16x8 av = *(const bf16x8*)&sV[cur][idx];
        oacc[db] = __builtin_amdgcn_mfma_f32_16x16x32_bf16(av, (ks ? t1.b : t0.b),
                                                           oacc[db], 0, 0, 0);
      }
    }
    __syncthreads();   // drains vmcnt (next tile landed) + LDS-read reuse fence
    cur ^= 1;
  }

  // ---- epilogue: denom = sum(p*tb) + sink weight 1.0 ----
  float lt = (l4[0] + l4[1]) + (l4[2] + l4[3]);
  lt += __shfl_xor(lt, 16, 64);
  lt += __shfl_xor(lt, 32, 64);
  float denom = lt + 1.0f;
  float inv = 1.0f / denom;
  float* op = out + (bhN + qg) * DH;
#pragma unroll
  for (int db = 0; db < 4; db++) {
    float4 o;
    o.x = oacc[db][0] * inv;
    o.y = oacc[db][1] * inv;
    o.z = oacc[db][2] * inv;
    o.w = oacc[db][3] * inv;
    *(float4*)(op + db * 16 + 4 * g) = o;
  }
}

extern "C" void kernel_launch(void* const* d_in, const int* in_sizes, int n_in,
                              void* d_out, int out_size, void* d_ws, size_t ws_size,
                              hipStream_t stream) {
  (void)in_sizes; (void)n_in; (void)out_size; (void)ws_size;
  const float* q = (const float*)d_in[0];
  const float* k = (const float*)d_in[1];
  const float* v = (const float*)d_in[2];
  float* out = (float*)d_out;

  // ws layout: K images 8 MiB | V images 8 MiB | tb 256 KiB
  char* ws = (char*)d_ws;
  unsigned short* wsK = (unsigned short*)ws;
  unsigned short* wsV = (unsigned short*)(ws + (8u << 20));
  float*          wsB = (float*)(ws + (16u << 20));

  build_ws<<<dim3(32, NT), dim3(256), 0, stream>>>(k, v, wsK, wsV, wsB);
  attend_l2_flash<<<dim3(32, NT), dim3(256), 0, stream>>>(q, wsK, wsV, wsB, out);
}

// Round 12
// 49.273 us; speedup vs baseline: 1.7543x; 1.0677x over previous
//
#include <hip/hip_runtime.h>

// L2-distance causal attention with zero-KV sink.
// B=2, H=16, N=2048, D=64. fp32 in/out, bf16 MFMA internally.
//
// Round 11 = Round 10 math + counted-vmcnt pipeline on the winning structure:
//   - No online-softmax machinery (sink pins max; bias folded into V' and tb).
//   - 3 LDS buffers (48 KB -> 3 blocks/CU), 2-deep staging; per tile ONE raw
//     s_barrier + s_waitcnt vmcnt(4): STAGE(t+2) stays in flight across the
//     barrier (never drain to 0 mid-loop). Tail uses vmcnt(0).
//   - tb (2^bias) lives in REGISTERS, loaded one tile ahead (removes 4 LDS
//     reads/wave-tile and the wid0 gl_lds4; uniform 4+4 VMEM per thread/iter).
//   - grid (32,32), y reversed so heavy q-blocks dispatch first.

#define NQ 2048
#define DH 64
#define NT 32   // KV tiles per sequence (2048/64)

typedef float f32x4 __attribute__((ext_vector_type(4)));
typedef __bf16 bf16x8 __attribute__((ext_vector_type(8)));
typedef unsigned short u16x8 __attribute__((ext_vector_type(8)));

union B8 { u16x8 u; bf16x8 b; };

__device__ __forceinline__ unsigned short f2b(float f) {
  unsigned int x = __builtin_bit_cast(unsigned int, f);
  unsigned int r = x + 0x7fffu + ((x >> 16) & 1u);   // RNE to bf16
  return (unsigned short)(r >> 16);
}
__device__ __forceinline__ float b2f(unsigned short u) {
  unsigned int t = ((unsigned int)u) << 16;
  return __builtin_bit_cast(float, t);
}

// K-slot permutation: slot s (bits c1 c0 g1 g0 r1 r0) holds key (c1 g1 g0 c0 r1 r0).
// Makes QK^T's C-layout scores be exactly the PV B-fragment values (no exchange).
__device__ __forceinline__ int kslot(int a) {
  return (a & 0x23) | ((a & 0x04) << 2) | ((a & 0x18) >> 1);
}

__device__ __forceinline__ void gl_lds16(const void* g, void* l) {
  __builtin_amdgcn_global_load_lds(
      (const __attribute__((address_space(1))) unsigned int*)g,
      (__attribute__((address_space(3))) unsigned int*)l, 16, 0, 0);
}

constexpr float QS = 0.3551784733906239f;   // 2*log2(e)/sqrt(66)
constexpr float BS = 0.17758923669531197f;  // log2(e)/sqrt(66)

// ---------------- kernel 1: build per-tile images ----------------
__global__ __launch_bounds__(256) void build_ws(
    const float* __restrict__ k, const float* __restrict__ v,
    unsigned short* __restrict__ wsK, unsigned short* __restrict__ wsV,
    float* __restrict__ wsB)
{
  const int bh = blockIdx.x;          // 0..31
  const int t  = blockIdx.y;          // 0..31
  const int tid  = threadIdx.x;
  const int wid  = tid >> 6;
  const int lane = tid & 63;
  const size_t bhN = (size_t)bh * NQ;
  const int tile64 = t * 64;
  const size_t tileId = (size_t)bh * NT + t;
  unsigned short* Kt = wsK + tileId * 4096;
  unsigned short* Vt = wsV + tileId * 4096;
  float*          Bt = wsB + tileId * 64;

  __shared__ float sTb[64];   // 2^{b_j} by KEY index (for the V pass)

  // K image (+ tb), slot-permuted, XOR-swizzled — exact LDS byte image.
#pragma unroll
  for (int i = 0; i < 4; i++) {
    int f  = i * 256 + tid;
    int kg = f >> 4, d4 = f & 15;
    int slot = kslot(kg);
    const float4* kp = (const float4*)(k + (bhN + tile64 + kg) * DH);
    float4 kk = kp[d4];
    unsigned short h0 = f2b(kk.x), h1 = f2b(kk.y), h2 = f2b(kk.z), h3 = f2b(kk.w);
    float a0 = b2f(h0), a1 = b2f(h1), a2 = b2f(h2), a3 = b2f(h3);
    float ss = a0*a0 + a1*a1 + a2*a2 + a3*a3;     // |k_bf|^2 partial
    ss += __shfl_xor(ss, 1, 64);
    ss += __shfl_xor(ss, 2, 64);
    ss += __shfl_xor(ss, 4, 64);
    ss += __shfl_xor(ss, 8, 64);
    if (d4 == 0) {
      float tb = __builtin_amdgcn_exp2f(-BS * ss);  // 2^{bias}
      Bt[slot] = tb;       // slot-permuted image for the attend kernel
      sTb[kg]  = tb;       // key-indexed for the V pass below
    }
    unsigned int w0 = (unsigned int)h0 | ((unsigned int)h1 << 16);
    unsigned int w1 = (unsigned int)h2 | ((unsigned int)h3 << 16);
    int idx = slot * 64 + ((d4 * 4) ^ ((slot & 7) << 3));
    uint2 wv; wv.x = w0; wv.y = w1;
    *(uint2*)&Kt[idx] = wv;
  }
  __syncthreads();

  // V^T image (identity slot order), XOR-swizzled, pre-scaled by 2^{b_j}.
#pragma unroll
  for (int jj = 0; jj < 4; jj++) {
    int kgb = jj * 16 + wid * 4;
    const float* vp = v + (bhN + tile64 + kgb) * DH + lane;
    float x0 = vp[0] * sTb[kgb + 0];
    float x1 = vp[DH] * sTb[kgb + 1];
    float x2 = vp[2 * DH] * sTb[kgb + 2];
    float x3 = vp[3 * DH] * sTb[kgb + 3];
    unsigned int w0 = (unsigned int)f2b(x0) | ((unsigned int)f2b(x1) << 16);
    unsigned int w1 = (unsigned int)f2b(x2) | ((unsigned int)f2b(x3) << 16);
    int idx = lane * 64 + (kgb ^ ((lane & 7) << 3));
    uint2 wv; wv.x = w0; wv.y = w1;
    *(uint2*)&Vt[idx] = wv;
  }
}

// ---------------- kernel 2: counted-vmcnt flash attention ----------------
__global__ __launch_bounds__(256) void attend_l2_flash(
    const float* __restrict__ q,
    const unsigned short* __restrict__ wsK,
    const unsigned short* __restrict__ wsV,
    const float* __restrict__ wsB,
    float* __restrict__ out)
{
  const int bh   = blockIdx.x;
  const int qt   = (gridDim.y - 1) - blockIdx.y;   // heavy tiles dispatch first
  const int qbase = qt * 64;
  const int tid  = threadIdx.x;
  const int wid  = tid >> 6;
  const int lane = tid & 63;
  const int g    = lane >> 4;
  const int qi   = lane & 15;
  const int qg   = qbase + wid * 16 + qi;          // this lane's query row
  const size_t bhN = (size_t)bh * NQ;

  __shared__ __align__(16) unsigned short sK[3][4096];   // 3-deep rotation
  __shared__ __align__(16) unsigned short sV[3][4096];

  // ---- Q fragments (single bf16 pass), hoisted ----
  const float* qrow = q + (bhN + qg) * DH;
  bf16x8 q8[2];
#pragma unroll
  for (int ks = 0; ks < 2; ks++) {
    B8 th;
#pragma unroll
    for (int j = 0; j < 8; j++)
      th.u[j] = f2b(qrow[ks * 32 + g * 8 + j] * QS);
    q8[ks] = th.b;
  }

  f32x4 oacc[4] = { {0,0,0,0}, {0,0,0,0}, {0,0,0,0}, {0,0,0,0} };
  f32x4 l4 = {0, 0, 0, 0};        // packed partial denominator

  const int ntiles = qt + 1;
  const size_t tbase = (size_t)bh * NT;
  const float* TB = wsB + tbase * 64;

  // tb for tile t -> 4 register vectors (per-lane slice, g-dependent)
  auto LTB = [&](int t, f32x4* tb) {
    const float* p = TB + t * 64 + 4 * g;
#pragma unroll
    for (int c = 0; c < 4; c++) tb[c] = *(const f32x4*)(p + 16 * c);
  };
  // stage kv-tile t: 4 gl_lds16 per thread (2 K + 2 V), linear DMA
  auto STAGE = [&](unsigned short* bK, unsigned short* bV, int t) {
    const char* Kt = (const char*)(wsK + (tbase + t) * 4096);
    const char* Vt = (const char*)(wsV + (tbase + t) * 4096);
#pragma unroll
    for (int c = 0; c < 2; c++) {
      int boff = wid * 2048 + c * 1024;
      gl_lds16(Kt + boff + lane * 16, (char*)bK + boff);
      gl_lds16(Vt + boff + lane * 16, (char*)bV + boff);
    }
  };

  unsigned short *kA = sK[0], *kB = sK[1], *kC = sK[2];
  unsigned short *vA = sV[0], *vB = sV[1], *vC = sV[2];
  f32x4 tb_cur[4], tb_nxt[4];

  // prologue: S0 | tb0 | S1  -> vmcnt(4) leaves S1 in flight, S0+tb0 done
  STAGE(kA, vA, 0);
  LTB(0, tb_cur);
  if (ntiles > 1) {
    STAGE(kB, vB, 1);
    asm volatile("s_waitcnt vmcnt(4)" ::: "memory");
  } else {
    asm volatile("s_waitcnt vmcnt(0)" ::: "memory");
  }
  __builtin_amdgcn_s_barrier();

  for (int t = 0; t < ntiles; t++) {
    const bool hasN1 = (t + 1 < ntiles);
    const bool hasN2 = (t + 2 < ntiles);
    if (hasN1) LTB(t + 1, tb_nxt);          // 4 VMEM (consumed next iter)
    __builtin_amdgcn_sched_barrier(0);
    if (hasN2) STAGE(kC, vC, t + 2);        // 4 VMEM (in flight across barrier)
    __builtin_amdgcn_sched_barrier(0);

    // ---- QK^T from kA, swapped: S^T = K . Q^T (8 MFMA) ----
    f32x4 sc[4] = { {0,0,0,0}, {0,0,0,0}, {0,0,0,0}, {0,0,0,0} };
#pragma unroll
    for (int c = 0; c < 4; c++) {
#pragma unroll
      for (int ks = 0; ks < 2; ks++) {
        int idx = (16 * c + qi) * 64 + ((ks * 32 + g * 8) ^ ((qi & 7) << 3));
        bf16x8 ak = *(const bf16x8*)&kA[idx];
        sc[c] = __builtin_amdgcn_mfma_f32_16x16x32_bf16(ak, q8[ks], sc[c], 0, 0, 0);
      }
    }

    // ---- causal mask on diag tile (masked -> exp2 gives exactly 0) ----
    if (t == ntiles - 1) {
      const int tile64 = t * 64;
#pragma unroll
      for (int c = 0; c < 4; c++)
#pragma unroll
        for (int r = 0; r < 4; r++) {
          int key = tile64 + 32 * (c >> 1) + 8 * g + 4 * (c & 1) + r; // pi(slot)
          if (key > qg) sc[c][r] = -1e30f;
        }
    }

    // ---- weights: p = exp2(s_raw); l += p * tb (no max, no rescale) ----
#pragma unroll
    for (int c = 0; c < 4; c++) {
#pragma unroll
      for (int r = 0; r < 4; r++) sc[c][r] = __builtin_amdgcn_exp2f(sc[c][r]);
#pragma unroll
      for (int r = 0; r < 4; r++) l4[r] = __builtin_fmaf(sc[c][r], tb_cur[c][r], l4[r]);
    }

    // ---- P repack (local by slot-permutation construction) ----
    B8 t0, t1;
#pragma unroll
    for (int j = 0; j < 8; j++) {
      t0.b[j] = (__bf16)sc[(j >> 2)][j & 3];
      t1.b[j] = (__bf16)sc[2 + (j >> 2)][j & 3];
    }

    // ---- PV from vA: O^T += V'^T . P^T (bias folded into V') ----
#pragma unroll
    for (int db = 0; db < 4; db++) {
#pragma unroll
      for (int ks = 0; ks < 2; ks++) {
        int idx = (db * 16 + qi) * 64 + ((ks * 32 + g * 8) ^ ((qi & 7) << 3));
        bf16x8 av = *(const bf16x8*)&vA[idx];
        oacc[db] = __builtin_amdgcn_mfma_f32_16x16x32_bf16(av, (ks ? t1.b : t0.b),
                                                           oacc[db], 0, 0, 0);
      }
    }

    // ---- counted wait: STAGE(t+1)+tb(t+1) done; STAGE(t+2) stays in flight ----
    if (hasN2) asm volatile("s_waitcnt vmcnt(4)" ::: "memory");
    else       asm volatile("s_waitcnt vmcnt(0)" ::: "memory");
    __builtin_amdgcn_s_barrier();

    // rotate buffers + tb
    unsigned short* tk = kA; kA = kB; kB = kC; kC = tk;
    unsigned short* tv = vA; vA = vB; vB = vC; vC = tv;
#pragma unroll
    for (int c = 0; c < 4; c++) tb_cur[c] = tb_nxt[c];
  }

  // ---- epilogue: denom = sum(p*tb) + sink weight 1.0 ----
  float lt = (l4[0] + l4[1]) + (l4[2] + l4[3]);
  lt += __shfl_xor(lt, 16, 64);
  lt += __shfl_xor(lt, 32, 64);
  float denom = lt + 1.0f;
  float inv = 1.0f / denom;
  float* op = out + (bhN + qg) * DH;
#pragma unroll
  for (int db = 0; db < 4; db++) {
    float4 o;
    o.x = oacc[db][0] * inv;
    o.y = oacc[db][1] * inv;
    o.z = oacc[db][2] * inv;
    o.w = oacc[db][3] * inv;
    *(float4*)(op + db * 16 + 4 * g) = o;
  }
}

extern "C" void kernel_launch(void* const* d_in, const int* in_sizes, int n_in,
                              void* d_out, int out_size, void* d_ws, size_t ws_size,
                              hipStream_t stream) {
  (void)in_sizes; (void)n_in; (void)out_size; (void)ws_size;
  const float* q = (const float*)d_in[0];
  const float* k = (const float*)d_in[1];
  const float* v = (const float*)d_in[2];
  float* out = (float*)d_out;

  // ws layout: K images 8 MiB | V images 8 MiB | tb 256 KiB
  char* ws = (char*)d_ws;
  unsigned short* wsK = (unsigned short*)ws;
  unsigned short* wsV = (unsigned short*)(ws + (8u << 20));
  float*          wsB = (float*)(ws + (16u << 20));

  build_ws<<<dim3(32, NT), dim3(256), 0, stream>>>(k, v, wsK, wsV, wsB);
  attend_l2_flash<<<dim3(32, NT), dim3(256), 0, stream>>>(q, wsK, wsV, wsB, out);
}